// Round 9
// baseline (156.619 us; speedup 1.0000x reference)
//
#include <hip/hip_runtime.h>
#include <hip/hip_fp16.h>
#include <math.h>

__device__ __forceinline__ float sigm(float x)  { return 1.0f / (1.0f + __expf(-x)); }
__device__ __forceinline__ float siluf(float x) { return x * sigm(x); }

typedef _Float16 half8  __attribute__((ext_vector_type(8)));
typedef _Float16 half4  __attribute__((ext_vector_type(4)));
typedef float    f32x4  __attribute__((ext_vector_type(4)));

// async global->LDS, 16 B/lane: LDS dest = wave-uniform base + lane*16 (packed!)
__device__ __forceinline__ void gld16(const void* g, void* l) {
    __builtin_amdgcn_global_load_lds(
        (const __attribute__((address_space(1))) unsigned*)g,
        (__attribute__((address_space(3))) unsigned*)l, 16, 0, 0);
}

// =======================================================================
// 2-term split GEMM core (unchanged from R8).
// =======================================================================
template <int MI, int AMODE>
__device__ __forceinline__ void gemm_core16(
    const __half* __restrict__ A16,
    const __half* __restrict__ Bhi, const __half* __restrict__ Blo,
    int nbs, int m0, int n0, int t, f32x4 (&acc)[MI][4])
{
    __shared__ short As[MI * 1024], BsHi[4096], BsLo[4096];
    const int lane = t & 63, wave = t >> 6;
    const int wm = (wave >> 1) * (MI << 4), wn = (wave & 1) << 6;
    const int fr = lane & 15, fq = lane >> 4;

    for (int kb = 0; kb < 8; ++kb) {
        __syncthreads();
#pragma unroll
        for (int hf = 0; hf < MI / 2; ++hf) {
            const int rr = wave * (MI << 3) + (hf << 4);
            size_t ga;
            if (AMODE == 0)
                ga = (((size_t)(kb * 8192 + m0 + rr)) << 5) + (lane << 3);
            else
                ga = (((size_t)(m0 + rr + (lane >> 2))) << 8) + (kb << 5) + ((lane & 3) << 3);
            gld16(A16 + ga, &As[rr << 5]);
        }
#pragma unroll
        for (int hf = 0; hf < 2; ++hf) {
            const int rr = (wave << 5) + (hf << 4);
            const size_t gb = (((size_t)(kb * nbs + n0 + rr)) << 5) + (lane << 3);
            gld16(Bhi + gb, &BsHi[rr << 5]);
            gld16(Blo + gb, &BsLo[rr << 5]);
        }
        __syncthreads();

        half8 a[MI], bh[4], bl[4];
#pragma unroll
        for (int i = 0; i < MI; ++i)
            a[i] = *(const half8*)&As[((wm + (i << 4) + fr) << 5) + (fq << 3)];
#pragma unroll
        for (int i = 0; i < 4; ++i) {
            const int boff = ((wn + (i << 4) + fr) << 5) + (fq << 3);
            bh[i] = *(const half8*)&BsHi[boff];
            bl[i] = *(const half8*)&BsLo[boff];
        }
#pragma unroll
        for (int mi = 0; mi < MI; ++mi)
#pragma unroll
            for (int ni = 0; ni < 4; ++ni) {
                acc[mi][ni] = __builtin_amdgcn_mfma_f32_16x16x32_f16(a[mi], bh[ni], acc[mi][ni], 0, 0, 0);
                acc[mi][ni] = __builtin_amdgcn_mfma_f32_16x16x32_f16(a[mi], bl[ni], acc[mi][ni], 0, 0, 0);
            }
    }
}

// =======================================================================
// Prep (unchanged from R8).
// =======================================================================
__global__ __launch_bounds__(256) void prep_kernel(
    const float* __restrict__ x, const float* __restrict__ Wqkv,
    const float* __restrict__ Wgate, const float* __restrict__ Wout,
    const float* __restrict__ Wwp, const float* __restrict__ bwp,
    __half* __restrict__ xh,
    __half* __restrict__ wqh, __half* __restrict__ wql,
    __half* __restrict__ wgh, __half* __restrict__ wgl,
    __half* __restrict__ woh, __half* __restrict__ wol,
    float* __restrict__ width, float* __restrict__ sharp)
{
    __shared__ float xs[32][260];
    const int t = threadIdx.x;
    const int blk = blockIdx.x;
    if (blk < 256) {
        const int row0 = blk << 5;
        for (int e = t; e < 2048; e += 256) {
            int r = e >> 6, cc = (e & 63) << 2;
            *(float4*)&xs[r][cc] = *(const float4*)&x[(size_t)(row0 + r) * 256 + cc];
        }
        __syncthreads();
        const int r = t >> 3, kb = t & 7;
        __half hibuf[32];
#pragma unroll
        for (int i = 0; i < 32; ++i)
            hibuf[i] = __float2half(xs[r][(kb << 5) + i]);
        const size_t ob = ((size_t)(kb * 8192 + row0 + r)) << 5;
#pragma unroll
        for (int i = 0; i < 4; ++i)
            *(int4*)&xh[ob + (i << 3)] = *(int4*)&hibuf[i << 3];
        float acc = 0.f;
#pragma unroll 8
        for (int k = 0; k < 256; ++k) acc += xs[r][k] * Wwp[k * 8 + kb];
        float s = sigm(siluf(acc + bwp[kb]));
        const int row = row0 + r;
        if (kb < 4) width[row * 4 + kb] = s * 4.242640687119285f + 0.5f;  // sqrt(18)
        else        sharp[row * 4 + kb - 4] = s * 9.5f + 0.5f;
    } else {
        const float* W; __half *Whi, *Wlo; int N, nb0, ncnt;
        if (blk < 288)      { W = Wqkv;  Whi = wqh; Wlo = wql; N = 768; nb0 = (blk - 256) * 24; ncnt = 24; }
        else if (blk < 296) { W = Wgate; Whi = wgh; Wlo = wgl; N = 256; nb0 = (blk - 288) * 32; ncnt = 32; }
        else                { W = Wout;  Whi = woh; Wlo = wol; N = 256; nb0 = (blk - 296) * 32; ncnt = 32; }
        for (int j = 0; j < ncnt; ++j)
            xs[j][t] = W[(size_t)t * N + nb0 + j];
        __syncthreads();
        for (int c = t; c < ncnt * 8; c += 256) {
            const int j = c >> 3, kb = c & 7;
            __half hibuf[32], lobuf[32];
#pragma unroll
            for (int i = 0; i < 32; ++i) {
                float v = xs[j][(kb << 5) + i];
                __half hv = __float2half(v);
                hibuf[i] = hv;
                lobuf[i] = __float2half(v - __half2float(hv));
            }
            const size_t ob = ((size_t)(kb * N + nb0 + j)) << 5;
#pragma unroll
            for (int i = 0; i < 4; ++i) {
                *(int4*)&Whi[ob + (i << 3)] = *(int4*)&hibuf[i << 3];
                *(int4*)&Wlo[ob + (i << 3)] = *(int4*)&lobuf[i << 3];
            }
        }
    }
}

// =======================================================================
// qkv GEMM + fused epilogue (unchanged from R8).
// =======================================================================
__global__ __launch_bounds__(256, 3) void gemm_qkv(
    const __half* __restrict__ xh,
    const __half* __restrict__ wqh, const __half* __restrict__ wql,
    const float* __restrict__ wq, const float* __restrict__ wk,
    __half* __restrict__ qh, __half* __restrict__ kh, __half* __restrict__ vh)
{
    const int t  = threadIdx.x;
    const int m0 = blockIdx.y << 7, n0 = blockIdx.x << 7;
    f32x4 acc[4][4] = {};
    gemm_core16<4, 0>(xh, wqh, wql, 768, m0, n0, t, acc);

    const int lane = t & 63, wave = t >> 6;
    const int wm = (wave >> 1) << 6, wn = (wave & 1) << 6;
    const int fr = lane & 15, fq = lane >> 4;
    const int gc0 = n0 + wn;
    const int seg = gc0 >> 8;
    const int h   = (gc0 >> 6) & 3;
    const int hc0 = h << 6;

#pragma unroll
    for (int mi = 0; mi < 4; ++mi)
#pragma unroll
        for (int ni = 0; ni < 4; ++ni)
#pragma unroll
            for (int r = 0; r < 4; ++r)
                acc[mi][ni][r] = siluf(acc[mi][ni][r]);

    if (seg == 2) {
#pragma unroll
        for (int mi = 0; mi < 4; ++mi)
#pragma unroll
            for (int r = 0; r < 4; ++r) {
                const size_t row = m0 + wm + (mi << 4) + (fq << 2) + r;
#pragma unroll
                for (int ni = 0; ni < 4; ++ni)
                    vh[row * 256 + hc0 + (ni << 4) + fr] = __float2half(acc[mi][ni][r]);
            }
    } else {
        const float* wnorm = seg ? wk : wq;
        float wv[4];
#pragma unroll
        for (int ni = 0; ni < 4; ++ni) wv[ni] = wnorm[(ni << 4) + fr];
        float cs[2], sn[2];
#pragma unroll
        for (int j = 0; j < 2; ++j) {
            const int d = (j << 4) + fr;
            const float freq = powf(10000.f, -(float)d * (1.f / 32.f));
            const float ang = (float)h * freq;
            cs[j] = cosf(ang); sn[j] = sinf(ang);
        }
        __half* dstbase = (seg ? kh : qh);
#pragma unroll
        for (int mi = 0; mi < 4; ++mi)
#pragma unroll
            for (int r = 0; r < 4; ++r) {
                float ss = acc[mi][0][r] * acc[mi][0][r] + acc[mi][1][r] * acc[mi][1][r]
                         + acc[mi][2][r] * acc[mi][2][r] + acc[mi][3][r] * acc[mi][3][r];
                ss += __shfl_xor(ss, 1); ss += __shfl_xor(ss, 2);
                ss += __shfl_xor(ss, 4); ss += __shfl_xor(ss, 8);
                const float rinv = 1.f / sqrtf(ss * (1.f / 64.f) + 1e-6f);
                float xv[4];
#pragma unroll
                for (int ni = 0; ni < 4; ++ni) xv[ni] = acc[mi][ni][r] * rinv * wv[ni];
                const float o0 = xv[0] * cs[0] - xv[2] * sn[0];
                const float o2 = xv[0] * sn[0] + xv[2] * cs[0];
                const float o1 = xv[1] * cs[1] - xv[3] * sn[1];
                const float o3 = xv[1] * sn[1] + xv[3] * cs[1];
                const size_t row = m0 + wm + (mi << 4) + (fq << 2) + r;
                __half* dst = dstbase + row * 256 + hc0;
                dst[fr]      = __float2half(o0);
                dst[16 + fr] = __float2half(o1);
                dst[32 + fr] = __float2half(o2);
                dst[48 + fr] = __float2half(o3);
            }
    }
}

// ---- gate GEMM (unchanged from R8) ----
__global__ __launch_bounds__(256, 3) void gemm_gate(
    const __half* __restrict__ vh,
    const __half* __restrict__ wgh, const __half* __restrict__ wgl,
    const float* __restrict__ bias, const float* __restrict__ attn_o,
    const float* __restrict__ sumsq4, const float* __restrict__ w_onorm,
    __half* __restrict__ mh)
{
    const int t  = threadIdx.x;
    const int m0 = blockIdx.y << 6, n0 = blockIdx.x << 7;
    f32x4 acc[2][4] = {};
    gemm_core16<2, 1>(vh, wgh, wgl, 256, m0, n0, t, acc);

    const int lane = t & 63, wave = t >> 6;
    const int wm = (wave >> 1) << 5, wn = (wave & 1) << 6;
    const int fr = lane & 15, fq = lane >> 4;

    float rmsf[2][4];
#pragma unroll
    for (int mi = 0; mi < 2; ++mi)
#pragma unroll
        for (int r = 0; r < 4; ++r) {
            const int m = m0 + wm + (mi << 4) + (fq << 2) + r;
            float4 s4 = *(const float4*)&sumsq4[(size_t)m * 4];
            rmsf[mi][r] = 1.f / sqrtf((s4.x + s4.y + s4.z + s4.w) * (1.f / 256.f) + 1e-6f);
        }

#pragma unroll
    for (int mi = 0; mi < 2; ++mi)
#pragma unroll
        for (int ni = 0; ni < 4; ++ni) {
            const int n  = n0 + wn + (ni << 4) + fr;
            const int mb = m0 + wm + (mi << 4) + (fq << 2);
            const float bb  = bias[n];
            const float won = w_onorm[n];
#pragma unroll
            for (int r = 0; r < 4; ++r) {
                const int m = mb + r;
                const float g  = sigm(siluf(acc[mi][ni][r] + bb));
                const float vv = __half2float(vh[(size_t)m * 256 + n]);
                const float oo = attn_o[(size_t)m * 256 + n] * rmsf[mi][r] * won;
                mh[(size_t)m * 256 + n] = __float2half(g * vv + (1.f - g) * oo);
            }
        }
}

// ---- final GEMM (unchanged from R8) ----
__global__ __launch_bounds__(256, 3) void gemm_out(
    const __half* __restrict__ mh,
    const __half* __restrict__ woh, const __half* __restrict__ wol,
    float* __restrict__ out)
{
    const int t  = threadIdx.x;
    const int m0 = blockIdx.y << 6, n0 = blockIdx.x << 7;
    f32x4 acc[2][4] = {};
    gemm_core16<2, 1>(mh, woh, wol, 256, m0, n0, t, acc);

    const int lane = t & 63, wave = t >> 6;
    const int wm = (wave >> 1) << 5, wn = (wave & 1) << 6;
    const int fr = lane & 15, fq = lane >> 4;
#pragma unroll
    for (int mi = 0; mi < 2; ++mi)
#pragma unroll
        for (int ni = 0; ni < 4; ++ni) {
            const int n  = n0 + wn + (ni << 4) + fr;
            const int mb = m0 + wm + (mi << 4) + (fq << 2);
#pragma unroll
            for (int r = 0; r < 4; ++r)
                out[(size_t)(mb + r) * 256 + n] = siluf(acc[mi][ni][r]);
        }
}

// =======================================================================
// Patch-GEMM local attention, R9:
//  - LDS 53248 B (PT=208) -> 3 blocks/CU, all 512 blocks co-resident
//  - K staged via global_load_lds with GLOBAL-side swizzle (no regs/writes)
//  - OOB masking moved to score phase (inb cndmask; kills garbage NaNs)
//  - Vt transpose: pair-merged b32 writes (26 instead of 50 b16)
//  - 3rd barrier -> lgkmcnt-only wait (PV reads own-wave P rows + stable Vt)
// =======================================================================
#define PT 208

__global__ __launch_bounds__(256, 3) void attn_mfma(
    const __half* __restrict__ qh, const __half* __restrict__ kh,
    const __half* __restrict__ vh, const float* __restrict__ width,
    const float* __restrict__ sharp, float* __restrict__ attn_o,
    float* __restrict__ sumsq4)
{
    __shared__ short smem[26624];          // 53248 B
    short* Ksh = smem;                     // [208][64], chunk-swizzled; overlaid by Psh [64][PT]
    short* Psh = smem;
    short* Vt  = smem + 13312;             // [64 d][PT]

    const int t = threadIdx.x;
    const int lane = t & 63, wave = t >> 6;
    const int fr = lane & 15, fq = lane >> 4;
    const int patch = blockIdx.x, h = blockIdx.y, b = blockIdx.z;
    const int pr0 = (patch >> 3) << 3, pc0 = (patch & 7) << 3;
    const size_t cbase = (((size_t)b << 20)) + ((size_t)h << 6);  // halves

    // ---- per-lane query meta (issued first) ----
    float wd[4], sh[4]; int lq[4];
#pragma unroll
    for (int r = 0; r < 4; ++r) {
        const int q = (wave << 4) + (fq << 2) + r;
        lq[r] = (pr0 + (q >> 3)) * 64 + pc0 + (q & 7);
        wd[r] = width[((b << 12) + lq[r]) * 4 + h];
        sh[r] = sharp[((b << 12) + lq[r]) * 4 + h];
    }

    // ---- K: DMA to LDS, swizzle on the global side ----
    // chunk c (8 rows) staged by wave c%4; lane i -> row 8c+(i>>3),
    // stored chunk i&7 must hold global chunk (i&7)^(row&7).
    {
        const int lr = lane >> 3;
        const int doff = (((lane & 7) ^ (lr & 7)) << 3);
#pragma unroll
        for (int ci = 0; ci < 7; ++ci) {
            const int c = wave + (ci << 2);
            if (c < 26) {                       // wave-uniform
                const int pr = (c << 3) + lr;
                const int pi = pr / 14, pj = pr - pi * 14;
                const int grc = min(max(pr0 - 3 + pi, 0), 63);
                const int gcc = min(max(pc0 - 3 + pj, 0), 63);
                gld16(kh + cbase + (size_t)((grc << 6) + gcc) * 256 + doff,
                      &Ksh[c << 9]);
            }
        }
    }

    // ---- Q straight into A-frags ----
    const int qrow = (wave << 4) + fr;
    const int lqr = (pr0 + (qrow >> 3)) * 64 + pc0 + (qrow & 7);
    const __half* qptr = qh + (((size_t)(b << 12) + lqr) << 8) + (h << 6) + (fq << 3);
    half8 a0 = *(const half8*)qptr;
    half8 a1 = *(const half8*)(qptr + 32);

    // ---- V: register loads (pairs) -> merged b32 transpose writes ----
    const int srow = t >> 5;               // 0..7
    const int d2 = (t & 31) << 1;
    unsigned v0[13], v1[13];
#pragma unroll
    for (int j = 0; j < 13; ++j) {
        const int p = (j << 4) + (srow << 1);
#pragma unroll
        for (int e = 0; e < 2; ++e) {
            const int pp = p + e;
            const int pi = pp / 14, pj = pp - pi * 14;
            const int gr = pr0 - 3 + pi, gc = pc0 - 3 + pj;
            const bool ok = (pp < 196) & ((unsigned)gr < 64u) & ((unsigned)gc < 64u);
            const int grc = min(max(gr, 0), 63), gcc = min(max(gc, 0), 63);
            const unsigned vv = *(const unsigned*)(vh + cbase + (size_t)((grc << 6) + gcc) * 256 + d2);
            (e ? v1 : v0)[j] = ok ? vv : 0u;
        }
    }
#pragma unroll
    for (int j = 0; j < 13; ++j) {
        const int p = (j << 4) + (srow << 1);       // even
        const unsigned lo = (v0[j] & 0xffffu) | (v1[j] << 16);          // {v[p].d2,   v[p+1].d2}
        const unsigned hi = (v0[j] >> 16) | (v1[j] & 0xffff0000u);      // {v[p].d2+1, v[p+1].d2+1}
        *(unsigned*)&Vt[d2 * PT + p]       = lo;
        *(unsigned*)&Vt[(d2 + 1) * PT + p] = hi;
    }
    __syncthreads();   // drains GLD vmcnt + LDS writes

    // ---- QK^T: 13 n-tiles ----
    f32x4 sc[13];
#pragma unroll
    for (int tl = 0; tl < 13; ++tl) {
        const int kr = (tl << 4) + fr;
        half8 b0 = *(const half8*)&Ksh[(kr << 6) + (((0 + fq) ^ (kr & 7)) << 3)];
        half8 b1 = *(const half8*)&Ksh[(kr << 6) + (((4 + fq) ^ (kr & 7)) << 3)];
        f32x4 z = {0.f, 0.f, 0.f, 0.f};
        z = __builtin_amdgcn_mfma_f32_16x16x32_f16(a0, b0, z, 0, 0, 0);
        sc[tl] = __builtin_amdgcn_mfma_f32_16x16x32_f16(a1, b1, z, 0, 0, 0);
    }

    // ---- mask + softmax (OOB/garbage handled here: inb cndmask) ----
    float mx[4] = {-3e38f, -3e38f, -3e38f, -3e38f};
#pragma unroll
    for (int tl = 0; tl < 13; ++tl) {
        const int p = (tl << 4) + fr;
        const int pi = p / 14, pj = p - pi * 14;
        const bool pvld = p < 196;
        const bool inb = pvld & ((unsigned)(pr0 - 3 + pi) < 64u) & ((unsigned)(pc0 - 3 + pj) < 64u);
#pragma unroll
        for (int r = 0; r < 4; ++r) {
            const int q = (wave << 4) + (fq << 2) + r;
            const int di = pi - 3 - ((q >> 3) & 7), dj = pj - 3 - (q & 7);
            const bool win = pvld & ((unsigned)(di + 3) <= 6u) & ((unsigned)(dj + 3) <= 6u);
            const float rel = sqrtf((float)(di * di + dj * dj));
            const float mk = sigm((wd[r] - rel) * sh[r]);
            const float s0 = inb ? sc[tl][r] * 0.125f : 0.f;   // unfold2d zero-pad; kills NaN
            float s = s0 - (1.f - mk) * 10000.f;
            s = win ? s : -3e38f;
            sc[tl][r] = s;
            mx[r] = fmaxf(mx[r], s);
        }
    }
#pragma unroll
    for (int r = 0; r < 4; ++r) {
        mx[r] = fmaxf(mx[r], __shfl_xor(mx[r], 1));
        mx[r] = fmaxf(mx[r], __shfl_xor(mx[r], 2));
        mx[r] = fmaxf(mx[r], __shfl_xor(mx[r], 4));
        mx[r] = fmaxf(mx[r], __shfl_xor(mx[r], 8));
    }
    float sm[4] = {0.f, 0.f, 0.f, 0.f};
#pragma unroll
    for (int tl = 0; tl < 13; ++tl)
#pragma unroll
        for (int r = 0; r < 4; ++r) {
            const float e = __expf(sc[tl][r] - mx[r]);
            sc[tl][r] = e; sm[r] += e;
        }
#pragma unroll
    for (int r = 0; r < 4; ++r) {
        sm[r] += __shfl_xor(sm[r], 1);
        sm[r] += __shfl_xor(sm[r], 2);
        sm[r] += __shfl_xor(sm[r], 4);
        sm[r] += __shfl_xor(sm[r], 8);
        sm[r] = 1.f / sm[r];
    }

    __syncthreads();   // all Ksh reads done before P overwrites (cross-wave)
#pragma unroll
    for (int tl = 0; tl < 13; ++tl)
#pragma unroll
        for (int r = 0; r < 4; ++r) {
            __half pv = __float2half(sc[tl][r] * sm[r]);
            Psh[((wave << 4) + (fq << 2) + r) * PT + (tl << 4) + fr] = *(short*)&pv;
        }
    // PV reads only THIS wave's P rows + Vt (stable since barrier 1):
    asm volatile("s_waitcnt lgkmcnt(0)" ::: "memory");

    // ---- PV: K = 192 (6x32) + 16 ----
    f32x4 o[4] = {};
    const int pra = (wave << 4) + fr;
#pragma unroll
    for (int s = 0; s < 6; ++s) {
        half8 pa = *(const half8*)&Psh[pra * PT + (fq << 3) + (s << 5)];
#pragma unroll
        for (int dt = 0; dt < 4; ++dt) {
            half8 vbf = *(const half8*)&Vt[((dt << 4) + fr) * PT + (fq << 3) + (s << 5)];
            o[dt] = __builtin_amdgcn_mfma_f32_16x16x32_f16(pa, vbf, o[dt], 0, 0, 0);
        }
    }
    {
        half4 pa = *(const half4*)&Psh[pra * PT + 192 + (fq << 2)];
#pragma unroll
        for (int dt = 0; dt < 4; ++dt) {
            half4 vbf = *(const half4*)&Vt[((dt << 4) + fr) * PT + 192 + (fq << 2)];
            o[dt] = __builtin_amdgcn_mfma_f32_16x16x16f16(pa, vbf, o[dt], 0, 0, 0);
        }
    }

#pragma unroll
    for (int r = 0; r < 4; ++r) {
        float ss = o[0][r]*o[0][r] + o[1][r]*o[1][r] + o[2][r]*o[2][r] + o[3][r]*o[3][r];
        ss += __shfl_xor(ss, 1); ss += __shfl_xor(ss, 2);
        ss += __shfl_xor(ss, 4); ss += __shfl_xor(ss, 8);
        const size_t rowb = (((size_t)(b << 12) + lq[r]) << 8) + h * 64;
#pragma unroll
        for (int dt = 0; dt < 4; ++dt)
            attn_o[rowb + (dt << 4) + fr] = o[dt][r];
        if (fr == 0) sumsq4[(((b << 12) + lq[r]) << 2) + h] = ss;
    }
}

extern "C" void kernel_launch(void* const* d_in, const int* in_sizes, int n_in,
                              void* d_out, int out_size, void* d_ws, size_t ws_size,
                              hipStream_t stream)
{
    const float* x      = (const float*)d_in[0];
    const float* W_qkv  = (const float*)d_in[1];
    const float* w_qn   = (const float*)d_in[2];
    const float* w_kn   = (const float*)d_in[3];
    const float* W_wp   = (const float*)d_in[4];
    const float* b_wp   = (const float*)d_in[5];
    const float* w_on   = (const float*)d_in[6];
    const float* W_out  = (const float*)d_in[7];
    const float* W_gate = (const float*)d_in[8];
    const float* b_gate = (const float*)d_in[9];
    float* out = (float*)d_out;

    __half* ws16 = (__half*)d_ws;
    __half* xh  = ws16;                    // [8][8192][32]
    __half* wqh = xh  + 2097152;           // [8][768][32]
    __half* wql = wqh + 196608;
    __half* wgh = wql + 196608;            // [8][256][32]
    __half* wgl = wgh + 65536;
    __half* woh = wgl + 65536;
    __half* wol = woh + 65536;
    __half* qhp = wol + 65536;             // [8192][256]
    __half* khp = qhp + 2097152;
    __half* vhp = khp + 2097152;
    __half* mh  = vhp + 2097152;
    float* attn_o = (float*)(mh + 2097152);  // [8192][256] f32
    float* widthp = attn_o + 2097152;
    float* sharpp = widthp + 32768;
    float* sumsq4 = sharpp + 32768;

    prep_kernel<<<304, 256, 0, stream>>>(x, W_qkv, W_gate, W_out, W_wp, b_wp,
                                         xh, wqh, wql, wgh, wgl, woh, wol,
                                         widthp, sharpp);
    gemm_qkv<<<dim3(6, 64), 256, 0, stream>>>(xh, wqh, wql, w_qn, w_kn,
                                              qhp, khp, vhp);
    attn_mfma<<<dim3(64, 4, 2), 256, 0, stream>>>(qhp, khp, vhp, widthp, sharpp,
                                                  attn_o, sumsq4);
    gemm_gate<<<dim3(2, 128), 256, 0, stream>>>(vhp, wgh, wgl, b_gate,
                                                attn_o, sumsq4, w_on, mh);
    gemm_out<<<dim3(2, 128), 256, 0, stream>>>(mh, woh, wol, out);
}